// Round 2
// baseline (1964.386 us; speedup 1.0000x reference)
//
#include <hip/hip_runtime.h>

typedef __bf16 bf16_t;
typedef __bf16 bf16x8 __attribute__((ext_vector_type(8)));
typedef __bf16 bf16x4 __attribute__((ext_vector_type(4)));
typedef float f32x4 __attribute__((ext_vector_type(4)));

#define SCALE 0.17677669529663687f

__device__ __forceinline__ f32x4 mfma16(bf16x8 a, bf16x8 b, f32x4 c) {
  return __builtin_amdgcn_mfma_f32_16x16x32_bf16(a, b, c, 0, 0, 0);
}

// XOR-swizzled LDS byte offset: 16B granule index XORed with (row&7).
// colByte < stride; works for any 2/8/16-byte aligned access within a granule.
__device__ __forceinline__ int swz(int row, int colByte, int strideB) {
  return row * strideB + ((((colByte >> 4) ^ (row & 7)) << 4) | (colByte & 15));
}

// ws layout: bf16 weights [0,147456) elems (294912 B), then bias f32 [6][64][64] (98304 B)
__global__ void prep(const float* __restrict__ qw, const float* __restrict__ kvw,
                     const float* __restrict__ pw, const float* __restrict__ table,
                     bf16_t* __restrict__ wsb, float* __restrict__ biasws) {
  int bid = blockIdx.x;
  if (bid < 144) {
    int i = bid * 256 + threadIdx.x;
#pragma unroll
    for (int j = 0; j < 4; ++j) {
      int e = i * 4 + j;
      float v;
      if (e < 36864) v = qw[e];
      else if (e < 110592) v = kvw[e - 36864];
      else v = pw[e - 110592];
      wsb[e] = (bf16_t)v;
    }
  } else {
    int e = (bid - 144) * 256 + threadIdx.x;  // [0, 24576)
    int h = e >> 12, rc = e & 4095, r = rc >> 6, c = rc & 63;
    int rel = ((r >> 3) - (c >> 3) + 7) * 15 + ((r & 7) - (c & 7) + 7);
    biasws[e] = table[rel * 6 + h];
  }
}

template <bool WS>
__device__ __forceinline__ bf16x8 ldw(const bf16_t* __restrict__ wb,
                                      const float* __restrict__ wf, int off) {
  if constexpr (WS) {
    return *(const bf16x8*)(wb + off);
  } else {
    const float4* p = (const float4*)(wf + off);
    float4 a = p[0], c = p[1];
    bf16x8 r;
    r[0] = (bf16_t)a.x; r[1] = (bf16_t)a.y; r[2] = (bf16_t)a.z; r[3] = (bf16_t)a.w;
    r[4] = (bf16_t)c.x; r[5] = (bf16_t)c.y; r[6] = (bf16_t)c.z; r[7] = (bf16_t)c.w;
    return r;
  }
}

// Persistent block: 256 blocks x 32 windows, 512 threads = 8 waves, 1 block/CU.
// LDS (bytes), all XOR-swizzled:
//   x1s @      0  [64][192] (aliased in attn: ps[8 waves][2 slots][16][64])
//   x2s @  24576  [64][192] (ps spill: waves 6,7)
//   qs  @  49152  [64][192] (aliased: att output)
//   ks  @  73728  [64][192]
//   vts @  98304  [192][64]   total 122880
template <bool WS>
__global__ __launch_bounds__(512, 2) void wca_main(
    const float* __restrict__ x1, const float* __restrict__ x2,
    const float* __restrict__ mask,
    const float* __restrict__ qw_f, const float* __restrict__ qb,
    const float* __restrict__ kvw_f, const float* __restrict__ kvb,
    const float* __restrict__ pw_f, const float* __restrict__ pb,
    const float* __restrict__ table,
    const bf16_t* __restrict__ wsb, const float* __restrict__ biasws,
    float* __restrict__ out) {
  extern __shared__ char smem[];
  const int t = threadIdx.x;
  const int w = t >> 6, l = t & 63, lo = l & 15, hi = l >> 4;
  const int bid = blockIdx.x;
  constexpr int X1S = 0, X2S = 24576, QS = 49152, KS = 73728, VTS = 98304;

  const bf16_t* q_wb = wsb;
  const bf16_t* kv_wb = wsb + 36864;
  const bf16_t* p_wb = wsb + 110592;

  // prologue: prefetch window `bid` into registers
  float4 p1[6], p2[6];
  {
    const float4* s1 = (const float4*)(x1 + (size_t)bid * 12288);
    const float4* s2 = (const float4*)(x2 + (size_t)bid * 12288);
#pragma unroll
    for (int it = 0; it < 3; ++it) {
      int idx = it * 512 + t;
      p1[2 * it] = s1[2 * idx]; p1[2 * it + 1] = s1[2 * idx + 1];
      p2[2 * it] = s2[2 * idx]; p2[2 * it + 1] = s2[2 * idx + 1];
    }
  }

  for (int iw_ = 0; iw_ < 32; ++iw_) {
    const int win = iw_ * 256 + bid;

    // ---------- stage regs -> LDS (convert f32->bf16) ----------
#pragma unroll
    for (int it = 0; it < 3; ++it) {
      int idx = it * 512 + t;
      int n = idx / 24, g = idx - n * 24;  // row, 16B-granule
      bf16x8 v;
      float4 a = p1[2 * it], b = p1[2 * it + 1];
      v[0] = (bf16_t)a.x; v[1] = (bf16_t)a.y; v[2] = (bf16_t)a.z; v[3] = (bf16_t)a.w;
      v[4] = (bf16_t)b.x; v[5] = (bf16_t)b.y; v[6] = (bf16_t)b.z; v[7] = (bf16_t)b.w;
      *(bf16x8*)(smem + X1S + swz(n, g * 16, 384)) = v;
      a = p2[2 * it]; b = p2[2 * it + 1];
      v[0] = (bf16_t)a.x; v[1] = (bf16_t)a.y; v[2] = (bf16_t)a.z; v[3] = (bf16_t)a.w;
      v[4] = (bf16_t)b.x; v[5] = (bf16_t)b.y; v[6] = (bf16_t)b.z; v[7] = (bf16_t)b.w;
      *(bf16x8*)(smem + X2S + swz(n, g * 16, 384)) = v;
    }
    // ---------- issue prefetch of next window (latency hides under compute) ----------
    if (iw_ < 31) {
      const float4* s1 = (const float4*)(x1 + (size_t)(win + 256) * 12288);
      const float4* s2 = (const float4*)(x2 + (size_t)(win + 256) * 12288);
#pragma unroll
      for (int it = 0; it < 3; ++it) {
        int idx = it * 512 + t;
        p1[2 * it] = s1[2 * idx]; p1[2 * it + 1] = s1[2 * idx + 1];
        p2[2 * it] = s2[2 * idx]; p2[2 * it + 1] = s2[2 * idx + 1];
      }
    }
    __syncthreads();

    // ---------- proj: waves 0-3 Q, waves 4-7 KV ----------
    if (w < 4) {
      f32x4 acc[4][3];
#pragma unroll
      for (int rt = 0; rt < 4; ++rt)
#pragma unroll
        for (int ct = 0; ct < 3; ++ct) { f32x4 z = {0.f, 0.f, 0.f, 0.f}; acc[rt][ct] = z; }
#pragma unroll
      for (int kk = 0; kk < 6; ++kk) {
        bf16x8 a[4];
#pragma unroll
        for (int rt = 0; rt < 4; ++rt)
          a[rt] = *(const bf16x8*)(smem + X1S + swz(rt * 16 + lo, (kk * 4 + hi) * 16, 384));
        bf16x8 bw[3];
#pragma unroll
        for (int ct = 0; ct < 3; ++ct) {
          int col = w * 48 + ct * 16 + lo;
          bw[ct] = ldw<WS>(q_wb, qw_f, col * 192 + kk * 32 + hi * 8);
        }
#pragma unroll
        for (int rt = 0; rt < 4; ++rt)
#pragma unroll
          for (int ct = 0; ct < 3; ++ct)
            acc[rt][ct] = mfma16(a[rt], bw[ct], acc[rt][ct]);
      }
#pragma unroll
      for (int ct = 0; ct < 3; ++ct) {
        int col = w * 48 + ct * 16 + lo;
        float bv = qb[col];
#pragma unroll
        for (int rt = 0; rt < 4; ++rt)
#pragma unroll
          for (int i = 0; i < 4; ++i)
            *(bf16_t*)(smem + QS + swz(rt * 16 + hi * 4 + i, col * 2, 384)) =
                (bf16_t)((acc[rt][ct][i] + bv) * SCALE);
      }
    } else {
      const int kw = w - 4;
      const int part = kw >> 1;       // 0 = K, 1 = V
      const int halfo = (kw & 1) * 96;
      f32x4 acc[4][6];
#pragma unroll
      for (int rt = 0; rt < 4; ++rt)
#pragma unroll
        for (int ct = 0; ct < 6; ++ct) { f32x4 z = {0.f, 0.f, 0.f, 0.f}; acc[rt][ct] = z; }
#pragma unroll
      for (int kk = 0; kk < 6; ++kk) {
        bf16x8 a[4];
#pragma unroll
        for (int rt = 0; rt < 4; ++rt)
          a[rt] = *(const bf16x8*)(smem + X2S + swz(rt * 16 + lo, (kk * 4 + hi) * 16, 384));
        bf16x8 bw[6];
#pragma unroll
        for (int ct = 0; ct < 6; ++ct) {
          int row = part * 192 + halfo + ct * 16 + lo;
          bw[ct] = ldw<WS>(kv_wb, kvw_f, row * 192 + kk * 32 + hi * 8);
        }
#pragma unroll
        for (int rt = 0; rt < 4; ++rt)
#pragma unroll
          for (int ct = 0; ct < 6; ++ct)
            acc[rt][ct] = mfma16(a[rt], bw[ct], acc[rt][ct]);
      }
#pragma unroll
      for (int ct = 0; ct < 6; ++ct) {
        int och = halfo + ct * 16 + lo;
        float bv = kvb[part * 192 + och];
        if (part == 0) {
#pragma unroll
          for (int rt = 0; rt < 4; ++rt)
#pragma unroll
            for (int i = 0; i < 4; ++i)
              *(bf16_t*)(smem + KS + swz(rt * 16 + hi * 4 + i, och * 2, 384)) =
                  (bf16_t)(acc[rt][ct][i] + bv);
        } else {
#pragma unroll
          for (int rt = 0; rt < 4; ++rt) {
            int n0 = rt * 16 + hi * 4;
            bf16x4 pk;
#pragma unroll
            for (int i = 0; i < 4; ++i) pk[i] = (bf16_t)(acc[rt][ct][i] + bv);
            *(bf16x4*)(smem + VTS + swz(och, n0 * 2, 128)) = pk;
          }
        }
      }
    }
    __syncthreads();

    // ---------- attention: wave = (rowtile w>>1, head-half w&1) ----------
    {
      const int rt3 = w >> 1, hh = w & 1, rbase = rt3 * 16;
      char* psb = smem + X1S + w * 4096;  // 2 slots x [16][64] swizzled, stride 128
      const float* maskp = mask + (size_t)(win & 1023) * 4096;
      float mval[4][4];
      int relidx[4][4];
#pragma unroll
      for (int i = 0; i < 4; ++i) {
        int r = rbase + hi * 4 + i;
#pragma unroll
        for (int ct = 0; ct < 4; ++ct) {
          int c = ct * 16 + lo;
          mval[i][ct] = maskp[r * 64 + c];
          if (!WS)
            relidx[i][ct] = (((r >> 3) - (c >> 3) + 7) * 15 + ((r & 7) - (c & 7) + 7)) * 6;
        }
      }
#pragma unroll
      for (int hq = 0; hq < 3; ++hq) {
        const int h = hh * 3 + hq;
        bf16x8 qa = *(const bf16x8*)(smem + QS + swz(rbase + lo, (h * 4 + hi) * 16, 384));
        f32x4 s[4];
#pragma unroll
        for (int ct = 0; ct < 4; ++ct) {
          f32x4 ci;
#pragma unroll
          for (int i = 0; i < 4; ++i) {
            float bvv;
            if (WS) bvv = biasws[h * 4096 + (rbase + hi * 4 + i) * 64 + ct * 16 + lo];
            else bvv = table[relidx[i][ct] + h];
            ci[i] = bvv + mval[i][ct];
          }
          bf16x8 kb = *(const bf16x8*)(smem + KS + swz(ct * 16 + lo, (h * 4 + hi) * 16, 384));
          s[ct] = mfma16(qa, kb, ci);
        }
        float m4[4] = {-1e30f, -1e30f, -1e30f, -1e30f};
#pragma unroll
        for (int ct = 0; ct < 4; ++ct)
#pragma unroll
          for (int i = 0; i < 4; ++i) m4[i] = fmaxf(m4[i], s[ct][i]);
#pragma unroll
        for (int d = 1; d < 16; d <<= 1)
#pragma unroll
          for (int i = 0; i < 4; ++i) m4[i] = fmaxf(m4[i], __shfl_xor(m4[i], d));
        float sm[4] = {0.f, 0.f, 0.f, 0.f};
#pragma unroll
        for (int ct = 0; ct < 4; ++ct)
#pragma unroll
          for (int i = 0; i < 4; ++i) {
            float p = __expf(s[ct][i] - m4[i]);
            s[ct][i] = p;
            sm[i] += p;
          }
#pragma unroll
        for (int d = 1; d < 16; d <<= 1)
#pragma unroll
          for (int i = 0; i < 4; ++i) sm[i] += __shfl_xor(sm[i], d);
        char* psw = psb + (hq & 1) * 2048;
#pragma unroll
        for (int ct = 0; ct < 4; ++ct)
#pragma unroll
          for (int i = 0; i < 4; ++i)
            *(bf16_t*)(psw + swz(hi * 4 + i, (ct * 16 + lo) * 2, 128)) = (bf16_t)s[ct][i];
        f32x4 o0 = {0.f, 0.f, 0.f, 0.f}, o1 = {0.f, 0.f, 0.f, 0.f};
#pragma unroll
        for (int k2 = 0; k2 < 2; ++k2) {
          bf16x8 pa = *(const bf16x8*)(psw + swz(lo, (k2 * 4 + hi) * 16, 128));
          bf16x8 v0 = *(const bf16x8*)(smem + VTS + swz(h * 32 + lo, (k2 * 4 + hi) * 16, 128));
          bf16x8 v1 = *(const bf16x8*)(smem + VTS + swz(h * 32 + 16 + lo, (k2 * 4 + hi) * 16, 128));
          o0 = mfma16(pa, v0, o0);
          o1 = mfma16(pa, v1, o1);
        }
#pragma unroll
        for (int i = 0; i < 4; ++i) {
          float rinv = 1.0f / sm[i];
          int r = rbase + hi * 4 + i;
          *(bf16_t*)(smem + QS + swz(r, (h * 32 + lo) * 2, 384)) = (bf16_t)(o0[i] * rinv);
          *(bf16_t*)(smem + QS + swz(r, (h * 32 + 16 + lo) * 2, 384)) = (bf16_t)(o1[i] * rinv);
        }
      }
    }
    __syncthreads();

    // ---------- out proj: wave = (rowtile w&3, col-group w>>2) ----------
    {
      const int rt4 = w & 3, cg = w >> 2;
      f32x4 acc[6];
#pragma unroll
      for (int ct = 0; ct < 6; ++ct) { f32x4 z = {0.f, 0.f, 0.f, 0.f}; acc[ct] = z; }
#pragma unroll
      for (int kk = 0; kk < 6; ++kk) {
        bf16x8 a = *(const bf16x8*)(smem + QS + swz(rt4 * 16 + lo, (kk * 4 + hi) * 16, 384));
        bf16x8 bw[6];
#pragma unroll
        for (int ct = 0; ct < 6; ++ct) {
          int col = cg * 96 + ct * 16 + lo;
          bw[ct] = ldw<WS>(p_wb, pw_f, col * 192 + kk * 32 + hi * 8);
        }
#pragma unroll
        for (int ct = 0; ct < 6; ++ct) acc[ct] = mfma16(a, bw[ct], acc[ct]);
      }
      float* outp = out + (size_t)win * 12288;
#pragma unroll
      for (int ct = 0; ct < 6; ++ct) {
        int col = cg * 96 + ct * 16 + lo;
        float bv = pb[col];
#pragma unroll
        for (int i = 0; i < 4; ++i)
          outp[(rt4 * 16 + hi * 4 + i) * 192 + col] = acc[ct][i] + bv;
      }
    }
    // no barrier needed: next stage writes x1s/x2s, disjoint from qs reads above;
    // post-stage __syncthreads orders everything before the next proj.
  }
}

extern "C" void kernel_launch(void* const* d_in, const int* in_sizes, int n_in,
                              void* d_out, int out_size, void* d_ws, size_t ws_size,
                              hipStream_t stream) {
  const float* x1 = (const float*)d_in[0];
  const float* x2 = (const float*)d_in[1];
  const float* mask = (const float*)d_in[2];
  const float* qw = (const float*)d_in[3];
  const float* qb = (const float*)d_in[4];
  const float* kvw = (const float*)d_in[5];
  const float* kvb = (const float*)d_in[6];
  const float* pw = (const float*)d_in[7];
  const float* pb = (const float*)d_in[8];
  const float* table = (const float*)d_in[9];
  float* out = (float*)d_out;
  bf16_t* wsb = (bf16_t*)d_ws;
  float* biasws = (float*)((char*)d_ws + 294912);
  const int LDS_BYTES = 122880;
  if (ws_size >= 393216) {
    prep<<<240, 256, 0, stream>>>(qw, kvw, pw, table, wsb, biasws);
    wca_main<true><<<256, 512, LDS_BYTES, stream>>>(x1, x2, mask, qw, qb, kvw, kvb,
                                                    pw, pb, table, wsb, biasws, out);
  } else {
    wca_main<false><<<256, 512, LDS_BYTES, stream>>>(x1, x2, mask, qw, qb, kvw, kvb,
                                                     pw, pb, table, wsb, biasws, out);
  }
}

// Round 3
// 1118.720 us; speedup vs baseline: 1.7559x; 1.7559x over previous
//
#include <hip/hip_runtime.h>

typedef __bf16 bf16_t;
typedef __bf16 bf16x8 __attribute__((ext_vector_type(8)));
typedef __bf16 bf16x4 __attribute__((ext_vector_type(4)));
typedef __bf16 bf16x2 __attribute__((ext_vector_type(2)));
typedef float f32x4 __attribute__((ext_vector_type(4)));

#define SCALE 0.17677669529663687f

__device__ __forceinline__ f32x4 mfma16(bf16x8 a, bf16x8 b, f32x4 c) {
  return __builtin_amdgcn_mfma_f32_16x16x32_bf16(a, b, c, 0, 0, 0);
}

// XOR-swizzled LDS byte offset: 16B-granule index XORed with (row&7).
__device__ __forceinline__ int swz(int row, int colByte, int strideB) {
  return row * strideB + ((((colByte >> 4) ^ (row & 7)) << 4) | (colByte & 15));
}

union CvtU { bf16x2 h; unsigned int u; };
union PaU { unsigned int u[4]; bf16x8 v; };

// ws: bf16 weights [0,147456) elems (294912 B), then bias f32 [6][64][64] (98304 B)
__global__ void prep(const float* __restrict__ qw, const float* __restrict__ kvw,
                     const float* __restrict__ pw, const float* __restrict__ table,
                     bf16_t* __restrict__ wsb, float* __restrict__ biasws) {
  int bid = blockIdx.x;
  if (bid < 144) {
    int i = bid * 256 + threadIdx.x;
#pragma unroll
    for (int j = 0; j < 4; ++j) {
      int e = i * 4 + j;
      float v;
      if (e < 36864) v = qw[e];
      else if (e < 110592) v = kvw[e - 36864];
      else v = pw[e - 110592];
      wsb[e] = (bf16_t)v;
    }
  } else {
    int e = (bid - 144) * 256 + threadIdx.x;  // [0, 24576)
    int h = e >> 12, rc = e & 4095, r = rc >> 6, c = rc & 63;
    int rel = ((r >> 3) - (c >> 3) + 7) * 15 + ((r & 7) - (c & 7) + 7);
    biasws[e] = table[rel * 6 + h];
  }
}

template <bool WS>
__device__ __forceinline__ bf16x8 ldw(const bf16_t* __restrict__ wb,
                                      const float* __restrict__ wf, int off) {
  if constexpr (WS) {
    return *(const bf16x8*)(wb + off);
  } else {
    const float4* p = (const float4*)(wf + off);
    float4 a = p[0], c = p[1];
    bf16x8 r;
    r[0] = (bf16_t)a.x; r[1] = (bf16_t)a.y; r[2] = (bf16_t)a.z; r[3] = (bf16_t)a.w;
    r[4] = (bf16_t)c.x; r[5] = (bf16_t)c.y; r[6] = (bf16_t)c.z; r[7] = (bf16_t)c.w;
    return r;
  }
}

// One block = one window. 512 threads = 8 waves. LDS = 3 x 24576 = 73728 B -> 2 blocks/CU.
//   XQ @     0 : x1 staged -> Q -> att-out   (stride 384, swizzled)
//   XK @ 24576 : x2 staged -> K              (stride 384, swizzled)
//   VT @ 49152 : V^T [192][64]               (stride 128, swizzled)
template <bool WS>
__global__ __launch_bounds__(512, 4) void wca_main(
    const float* __restrict__ x1, const float* __restrict__ x2,
    const float* __restrict__ mask,
    const float* __restrict__ qw_f, const float* __restrict__ qb,
    const float* __restrict__ kvw_f, const float* __restrict__ kvb,
    const float* __restrict__ pw_f, const float* __restrict__ pb,
    const float* __restrict__ table,
    const bf16_t* __restrict__ wsb, const float* __restrict__ biasws,
    float* __restrict__ out) {
  extern __shared__ char smem[];
  char* XQ = smem;
  char* XK = smem + 24576;
  char* VT = smem + 49152;

  const int t = threadIdx.x;
  const int w = t >> 6, l = t & 63, lo = l & 15, hi = l >> 4;
  const int b = blockIdx.x;

  const bf16_t* q_wb = wsb;
  const bf16_t* kv_wb = wsb + 36864;
  const bf16_t* p_wb = wsb + 110592;

  // ---------- stage x1 -> XQ, x2 -> XK (f32 -> bf16, swizzled) ----------
  {
    const float4* s1 = (const float4*)(x1 + (size_t)b * 12288);
    const float4* s2 = (const float4*)(x2 + (size_t)b * 12288);
#pragma unroll
    for (int it = 0; it < 3; ++it) {
      int idx = it * 512 + t;           // 8-float group id, [0,1536)
      int n = idx / 24, g = idx - n * 24;
      float4 a = s1[2 * idx], c = s1[2 * idx + 1];
      bf16x8 v;
      v[0] = (bf16_t)a.x; v[1] = (bf16_t)a.y; v[2] = (bf16_t)a.z; v[3] = (bf16_t)a.w;
      v[4] = (bf16_t)c.x; v[5] = (bf16_t)c.y; v[6] = (bf16_t)c.z; v[7] = (bf16_t)c.w;
      *(bf16x8*)(XQ + swz(n, g * 16, 384)) = v;
      a = s2[2 * idx]; c = s2[2 * idx + 1];
      v[0] = (bf16_t)a.x; v[1] = (bf16_t)a.y; v[2] = (bf16_t)a.z; v[3] = (bf16_t)a.w;
      v[4] = (bf16_t)c.x; v[5] = (bf16_t)c.y; v[6] = (bf16_t)c.z; v[7] = (bf16_t)c.w;
      *(bf16x8*)(XK + swz(n, g * 16, 384)) = v;
    }
  }
  __syncthreads();

  // ---------- proj: waves 0-3 Q (from XQ), waves 4-7 KV (from XK) ----------
  f32x4 qacc[4][3];   // Q waves
  f32x4 kacc[4][6];   // K waves (4,5); V waves (6,7) write VT before barrier
  if (w < 4) {
#pragma unroll
    for (int rt = 0; rt < 4; ++rt)
#pragma unroll
      for (int ct = 0; ct < 3; ++ct) { f32x4 z = {0.f,0.f,0.f,0.f}; qacc[rt][ct] = z; }
#pragma unroll
    for (int kk = 0; kk < 6; ++kk) {
      bf16x8 a[4];
#pragma unroll
      for (int rt = 0; rt < 4; ++rt)
        a[rt] = *(const bf16x8*)(XQ + swz(rt * 16 + lo, (kk * 4 + hi) * 16, 384));
      bf16x8 bw[3];
#pragma unroll
      for (int ct = 0; ct < 3; ++ct) {
        int col = w * 48 + ct * 16 + lo;
        bw[ct] = ldw<WS>(q_wb, qw_f, col * 192 + kk * 32 + hi * 8);
      }
#pragma unroll
      for (int rt = 0; rt < 4; ++rt)
#pragma unroll
        for (int ct = 0; ct < 3; ++ct)
          qacc[rt][ct] = mfma16(a[rt], bw[ct], qacc[rt][ct]);
    }
  } else {
    const int kw = w - 4;
    const int part = kw >> 1;          // 0 = K (waves 4,5), 1 = V (waves 6,7)
    const int halfo = (kw & 1) * 96;
#pragma unroll
    for (int rt = 0; rt < 4; ++rt)
#pragma unroll
      for (int ct = 0; ct < 6; ++ct) { f32x4 z = {0.f,0.f,0.f,0.f}; kacc[rt][ct] = z; }
#pragma unroll
    for (int kk = 0; kk < 6; ++kk) {
      bf16x8 a[4];
#pragma unroll
      for (int rt = 0; rt < 4; ++rt)
        a[rt] = *(const bf16x8*)(XK + swz(rt * 16 + lo, (kk * 4 + hi) * 16, 384));
      bf16x8 bw[6];
#pragma unroll
      for (int ct = 0; ct < 6; ++ct) {
        int row = part * 192 + halfo + ct * 16 + lo;
        bw[ct] = ldw<WS>(kv_wb, kvw_f, row * 192 + kk * 32 + hi * 8);
      }
#pragma unroll
      for (int rt = 0; rt < 4; ++rt)
#pragma unroll
        for (int ct = 0; ct < 6; ++ct)
          kacc[rt][ct] = mfma16(a[rt], bw[ct], kacc[rt][ct]);
    }
    if (part == 1) {
      // V^T into fresh region VT — safe before the barrier
#pragma unroll
      for (int ct = 0; ct < 6; ++ct) {
        int och = halfo + ct * 16 + lo;
        float bv = kvb[192 + och];
#pragma unroll
        for (int rt = 0; rt < 4; ++rt) {
          int n0 = rt * 16 + hi * 4;
          bf16x4 pk;
#pragma unroll
          for (int i = 0; i < 4; ++i) pk[i] = (bf16_t)(kacc[rt][ct][i] + bv);
          *(bf16x4*)(VT + swz(och, n0 * 2, 128)) = pk;
        }
      }
    }
  }
  __syncthreads();  // all reads of XQ/XK complete

  if (w < 4) {
#pragma unroll
    for (int ct = 0; ct < 3; ++ct) {
      int col = w * 48 + ct * 16 + lo;
      float bv = qb[col];
#pragma unroll
      for (int rt = 0; rt < 4; ++rt)
#pragma unroll
        for (int i = 0; i < 4; ++i)
          *(bf16_t*)(XQ + swz(rt * 16 + hi * 4 + i, col * 2, 384)) =
              (bf16_t)((qacc[rt][ct][i] + bv) * SCALE);
    }
  } else if (((w - 4) >> 1) == 0) {
    const int halfo = ((w - 4) & 1) * 96;
#pragma unroll
    for (int ct = 0; ct < 6; ++ct) {
      int och = halfo + ct * 16 + lo;
      float bv = kvb[och];
#pragma unroll
      for (int rt = 0; rt < 4; ++rt)
#pragma unroll
        for (int i = 0; i < 4; ++i)
          *(bf16_t*)(XK + swz(rt * 16 + hi * 4 + i, och * 2, 384)) =
              (bf16_t)(kacc[rt][ct][i] + bv);
    }
  }
  __syncthreads();  // Q, K, V^T all ready

  // ---------- attention: wave = (rowtile w>>1, head-half w&1), swapped QK^T ----------
  {
    const int rt3 = w >> 1, hh = w & 1, rbase = rt3 * 16;
    const int r = rbase + lo;  // this lane's softmax row (q)
    const float* maskp = mask + (size_t)(b & 1023) * 4096 + r * 64;
    f32x4 mk[4];
    int relidx[4][4];
#pragma unroll
    for (int ct = 0; ct < 4; ++ct) {
      mk[ct] = *(const f32x4*)(maskp + ct * 16 + hi * 4);
      if (!WS) {
#pragma unroll
        for (int i = 0; i < 4; ++i) {
          int c = ct * 16 + hi * 4 + i;
          relidx[ct][i] = (((r >> 3) - (c >> 3) + 7) * 15 + ((r & 7) - (c & 7) + 7)) * 6;
        }
      }
    }
#pragma unroll
    for (int hq = 0; hq < 3; ++hq) {
      const int h = hh * 3 + hq;
      bf16x8 qa = *(const bf16x8*)(XQ + swz(r, h * 64 + hi * 16, 384));
      f32x4 s[4];
#pragma unroll
      for (int ct = 0; ct < 4; ++ct) {
        f32x4 ci;
        if (WS) {
          ci = *(const f32x4*)(biasws + h * 4096 + r * 64 + ct * 16 + hi * 4);
        } else {
#pragma unroll
          for (int i = 0; i < 4; ++i) ci[i] = table[relidx[ct][i] + h];
        }
        ci += mk[ct];
        bf16x8 ka = *(const bf16x8*)(XK + swz(ct * 16 + lo, h * 64 + hi * 16, 384));
        s[ct] = mfma16(ka, qa, ci);  // S^T: lane holds S[r][c=ct*16+hi*4+i]
      }
      float mx = -1e30f;
#pragma unroll
      for (int ct = 0; ct < 4; ++ct)
#pragma unroll
        for (int i = 0; i < 4; ++i) mx = fmaxf(mx, s[ct][i]);
      mx = fmaxf(mx, __shfl_xor(mx, 16));
      mx = fmaxf(mx, __shfl_xor(mx, 32));
      float sum = 0.f;
#pragma unroll
      for (int ct = 0; ct < 4; ++ct)
#pragma unroll
        for (int i = 0; i < 4; ++i) {
          float p = __expf(s[ct][i] - mx);
          s[ct][i] = p;
          sum += p;
        }
      sum += __shfl_xor(sum, 16);
      sum += __shfl_xor(sum, 32);
      float rinv = 1.0f / sum;
      // pack normalized P pairs: word[ct][i2] = bf16x2(P[r][ct*16+hi*4+2*i2], +1)
      unsigned int word[4][2];
#pragma unroll
      for (int ct = 0; ct < 4; ++ct)
#pragma unroll
        for (int i2 = 0; i2 < 2; ++i2) {
          CvtU cu;
          cu.h[0] = (bf16_t)(s[ct][2 * i2] * rinv);
          cu.h[1] = (bf16_t)(s[ct][2 * i2 + 1] * rinv);
          word[ct][i2] = cu.u;
        }
      // PV: build A-frag P[r' = rbase+lo][k-run] via shfl word-pulls
      f32x4 o0 = {0.f, 0.f, 0.f, 0.f}, o1 = {0.f, 0.f, 0.f, 0.f};
#pragma unroll
      for (int k2 = 0; k2 < 2; ++k2) {
        PaU pa;
#pragma unroll
        for (int j2 = 0; j2 < 4; ++j2) {
          int src = lo + ((hi & 1) << 5) + ((j2 >> 1) << 4);
          unsigned int wa = (unsigned int)__shfl((int)word[2 * k2][j2 & 1], src);
          unsigned int wb = (unsigned int)__shfl((int)word[2 * k2 + 1][j2 & 1], src);
          pa.u[j2] = (hi & 2) ? wb : wa;
        }
        bf16x8 v0 = *(const bf16x8*)(VT + swz(h * 32 + lo, k2 * 64 + hi * 16, 128));
        bf16x8 v1 = *(const bf16x8*)(VT + swz(h * 32 + 16 + lo, k2 * 64 + hi * 16, 128));
        o0 = mfma16(pa.v, v0, o0);
        o1 = mfma16(pa.v, v1, o1);
      }
#pragma unroll
      for (int i = 0; i < 4; ++i) {
        int rr = rbase + hi * 4 + i;
        *(bf16_t*)(XQ + swz(rr, h * 64 + lo * 2, 384)) = (bf16_t)o0[i];
        *(bf16_t*)(XQ + swz(rr, h * 64 + 32 + lo * 2, 384)) = (bf16_t)o1[i];
      }
    }
  }
  __syncthreads();

  // ---------- out proj: wave = (rowtile w&3, col-group w>>2) ----------
  {
    const int rt4 = w & 3, cg = w >> 2;
    f32x4 acc[6];
#pragma unroll
    for (int ct = 0; ct < 6; ++ct) { f32x4 z = {0.f,0.f,0.f,0.f}; acc[ct] = z; }
#pragma unroll
    for (int kk = 0; kk < 6; ++kk) {
      bf16x8 a = *(const bf16x8*)(XQ + swz(rt4 * 16 + lo, (kk * 4 + hi) * 16, 384));
      bf16x8 bw[6];
#pragma unroll
      for (int ct = 0; ct < 6; ++ct) {
        int col = cg * 96 + ct * 16 + lo;
        bw[ct] = ldw<WS>(p_wb, pw_f, col * 192 + kk * 32 + hi * 8);
      }
#pragma unroll
      for (int ct = 0; ct < 6; ++ct) acc[ct] = mfma16(a, bw[ct], acc[ct]);
    }
    float* outp = out + (size_t)b * 12288;
#pragma unroll
    for (int ct = 0; ct < 6; ++ct) {
      int col = cg * 96 + ct * 16 + lo;
      float bv = pb[col];
#pragma unroll
      for (int i = 0; i < 4; ++i)
        outp[(rt4 * 16 + hi * 4 + i) * 192 + col] = acc[ct][i] + bv;
    }
  }
}

extern "C" void kernel_launch(void* const* d_in, const int* in_sizes, int n_in,
                              void* d_out, int out_size, void* d_ws, size_t ws_size,
                              hipStream_t stream) {
  const float* x1 = (const float*)d_in[0];
  const float* x2 = (const float*)d_in[1];
  const float* mask = (const float*)d_in[2];
  const float* qw = (const float*)d_in[3];
  const float* qb = (const float*)d_in[4];
  const float* kvw = (const float*)d_in[5];
  const float* kvb = (const float*)d_in[6];
  const float* pw = (const float*)d_in[7];
  const float* pb = (const float*)d_in[8];
  const float* table = (const float*)d_in[9];
  float* out = (float*)d_out;
  bf16_t* wsb = (bf16_t*)d_ws;
  float* biasws = (float*)((char*)d_ws + 294912);
  const int LDS_BYTES = 73728;
  if (ws_size >= 393216) {
    prep<<<240, 256, 0, stream>>>(qw, kvw, pw, table, wsb, biasws);
    wca_main<true><<<8192, 512, LDS_BYTES, stream>>>(x1, x2, mask, qw, qb, kvw, kvb,
                                                     pw, pb, table, wsb, biasws, out);
  } else {
    wca_main<false><<<8192, 512, LDS_BYTES, stream>>>(x1, x2, mask, qw, qb, kvw, kvb,
                                                      pw, pb, table, wsb, biasws, out);
  }
}

// Round 4
// 939.908 us; speedup vs baseline: 2.0900x; 1.1902x over previous
//
#include <hip/hip_runtime.h>

typedef __bf16 bf16_t;
typedef __bf16 bf16x8 __attribute__((ext_vector_type(8)));
typedef __bf16 bf16x4 __attribute__((ext_vector_type(4)));
typedef __bf16 bf16x2 __attribute__((ext_vector_type(2)));
typedef float f32x4 __attribute__((ext_vector_type(4)));

#define SCALE 0.17677669529663687f

__device__ __forceinline__ f32x4 mfma16(bf16x8 a, bf16x8 b, f32x4 c) {
  return __builtin_amdgcn_mfma_f32_16x16x32_bf16(a, b, c, 0, 0, 0);
}

// XOR-swizzled LDS byte offset: 16B-granule index XORed with (row&7).
__device__ __forceinline__ int swz(int row, int colByte, int strideB) {
  return row * strideB + ((((colByte >> 4) ^ (row & 7)) << 4) | (colByte & 15));
}

union CvtU { bf16x2 h; unsigned int u; };
union PaU { unsigned int u[4]; bf16x8 v; };

// ws: bf16 weights [0,147456) elems (294912 B), then bias f32 [6][64][64] (98304 B)
__global__ void prep(const float* __restrict__ qw, const float* __restrict__ kvw,
                     const float* __restrict__ pw, const float* __restrict__ table,
                     bf16_t* __restrict__ wsb, float* __restrict__ biasws) {
  int bid = blockIdx.x;
  if (bid < 144) {
    int i = bid * 256 + threadIdx.x;
#pragma unroll
    for (int j = 0; j < 4; ++j) {
      int e = i * 4 + j;
      float v;
      if (e < 36864) v = qw[e];
      else if (e < 110592) v = kvw[e - 36864];
      else v = pw[e - 110592];
      wsb[e] = (bf16_t)v;
    }
  } else {
    int e = (bid - 144) * 256 + threadIdx.x;  // [0, 24576)
    int h = e >> 12, rc = e & 4095, r = rc >> 6, c = rc & 63;
    int rel = ((r >> 3) - (c >> 3) + 7) * 15 + ((r & 7) - (c & 7) + 7);
    biasws[e] = table[rel * 6 + h];
  }
}

template <bool WS>
__device__ __forceinline__ bf16x8 ldw(const bf16_t* __restrict__ wb,
                                      const float* __restrict__ wf, int off) {
  if constexpr (WS) {
    return *(const bf16x8*)(wb + off);
  } else {
    const float4* p = (const float4*)(wf + off);
    float4 a = p[0], c = p[1];
    bf16x8 r;
    r[0] = (bf16_t)a.x; r[1] = (bf16_t)a.y; r[2] = (bf16_t)a.z; r[3] = (bf16_t)a.w;
    r[4] = (bf16_t)c.x; r[5] = (bf16_t)c.y; r[6] = (bf16_t)c.z; r[7] = (bf16_t)c.w;
    return r;
  }
}

// One block = one window. 512 threads = 8 waves. LDS = 3 x 24576 = 73728 B -> 2 blocks/CU.
//   R0 @     0 : x2 staged -> Q           (stride 384, swizzled)
//   R1 @ 24576 : K -> att-out (per-head)  (stride 384, swizzled)
//   R2 @ 49152 : V^T [192][64]            (stride 128, swizzled)
// No accumulator lives across a barrier (round-3 spill post-mortem).
template <bool WS>
__global__ __attribute__((amdgpu_flat_work_group_size(512, 512),
                          amdgpu_waves_per_eu(4, 4)))
void wca_main(
    const float* __restrict__ x1, const float* __restrict__ x2,
    const float* __restrict__ mask,
    const float* __restrict__ qw_f, const float* __restrict__ qb,
    const float* __restrict__ kvw_f, const float* __restrict__ kvb,
    const float* __restrict__ pw_f, const float* __restrict__ pb,
    const float* __restrict__ table,
    const bf16_t* __restrict__ wsb, const float* __restrict__ biasws,
    float* __restrict__ out) {
  extern __shared__ char smem[];
  char* R0 = smem;
  char* R1 = smem + 24576;
  char* R2 = smem + 49152;

  const int t = threadIdx.x;
  const int w = t >> 6, l = t & 63, lo = l & 15, hi = l >> 4;
  const int b = blockIdx.x;

  const bf16_t* q_wb = wsb;
  const bf16_t* kv_wb = wsb + 36864;
  const bf16_t* p_wb = wsb + 110592;

  // ---------- stage x2 -> R0 (f32 -> bf16, swizzled) ----------
  {
    const float4* s2 = (const float4*)(x2 + (size_t)b * 12288);
#pragma unroll
    for (int it = 0; it < 3; ++it) {
      int idx = it * 512 + t;  // 8-float group id, [0,1536)
      int n = idx / 24, g = idx - n * 24;
      float4 a = s2[2 * idx], c = s2[2 * idx + 1];
      bf16x8 v;
      v[0] = (bf16_t)a.x; v[1] = (bf16_t)a.y; v[2] = (bf16_t)a.z; v[3] = (bf16_t)a.w;
      v[4] = (bf16_t)c.x; v[5] = (bf16_t)c.y; v[6] = (bf16_t)c.z; v[7] = (bf16_t)c.w;
      *(bf16x8*)(R0 + swz(n, g * 16, 384)) = v;
    }
  }
  __syncthreads();

  // ---------- phase A: KV proj, all 8 waves ----------
  // wave w: cols w*48 .. w*48+47 of the 384-wide KV output
  //   w<4 -> K cols w*48..  ; w>=4 -> V cols (w-4)*48..
  // kv weight row and kvb index are both w*48 + ct*16 + lo for all w.
  {
    f32x4 acc[4][3];
#pragma unroll
    for (int rt = 0; rt < 4; ++rt)
#pragma unroll
      for (int ct = 0; ct < 3; ++ct) { f32x4 z = {0.f, 0.f, 0.f, 0.f}; acc[rt][ct] = z; }
#pragma unroll
    for (int kk = 0; kk < 6; ++kk) {
      bf16x8 a[4];
#pragma unroll
      for (int rt = 0; rt < 4; ++rt)
        a[rt] = *(const bf16x8*)(R0 + swz(rt * 16 + lo, (kk * 4 + hi) * 16, 384));
      bf16x8 bw[3];
#pragma unroll
      for (int ct = 0; ct < 3; ++ct) {
        int row = w * 48 + ct * 16 + lo;
        bw[ct] = ldw<WS>(kv_wb, kvw_f, row * 192 + kk * 32 + hi * 8);
      }
#pragma unroll
      for (int rt = 0; rt < 4; ++rt)
#pragma unroll
        for (int ct = 0; ct < 3; ++ct)
          acc[rt][ct] = mfma16(a[rt], bw[ct], acc[rt][ct]);
    }
    if (w < 4) {
      // K row-major into R1
#pragma unroll
      for (int ct = 0; ct < 3; ++ct) {
        int och = w * 48 + ct * 16 + lo;
        float bv = kvb[och];
#pragma unroll
        for (int rt = 0; rt < 4; ++rt)
#pragma unroll
          for (int i = 0; i < 4; ++i)
            *(bf16_t*)(R1 + swz(rt * 16 + hi * 4 + i, och * 2, 384)) =
                (bf16_t)(acc[rt][ct][i] + bv);
      }
    } else {
      // V^T into R2
#pragma unroll
      for (int ct = 0; ct < 3; ++ct) {
        int och = (w - 4) * 48 + ct * 16 + lo;
        float bv = kvb[192 + och];
#pragma unroll
        for (int rt = 0; rt < 4; ++rt) {
          int n0 = rt * 16 + hi * 4;
          bf16x4 pk;
#pragma unroll
          for (int i = 0; i < 4; ++i) pk[i] = (bf16_t)(acc[rt][ct][i] + bv);
          *(bf16x4*)(R2 + swz(och, n0 * 2, 128)) = pk;
        }
      }
    }
  }
  __syncthreads();  // x2 reads done; K, V^T ready

  // ---------- phase B: Q proj from GLOBAL x1, all 8 waves ----------
  // wave w: rt = w&3 (rows rt*16..rt*16+15), cg = w>>2 (cols cg*96..cg*96+95)
  {
    const int rt = w & 3, cg = w >> 2;
    const float4* x1p = (const float4*)(x1 + (size_t)b * 12288 + (rt * 16 + lo) * 192);
    float4 xa[6], xb[6];
#pragma unroll
    for (int kk = 0; kk < 6; ++kk) {
      xa[kk] = x1p[kk * 8 + hi * 2];
      xb[kk] = x1p[kk * 8 + hi * 2 + 1];
    }
    f32x4 acc[6];
#pragma unroll
    for (int ct = 0; ct < 6; ++ct) { f32x4 z = {0.f, 0.f, 0.f, 0.f}; acc[ct] = z; }
#pragma unroll
    for (int kk = 0; kk < 6; ++kk) {
      bf16x8 a;
      a[0] = (bf16_t)xa[kk].x; a[1] = (bf16_t)xa[kk].y;
      a[2] = (bf16_t)xa[kk].z; a[3] = (bf16_t)xa[kk].w;
      a[4] = (bf16_t)xb[kk].x; a[5] = (bf16_t)xb[kk].y;
      a[6] = (bf16_t)xb[kk].z; a[7] = (bf16_t)xb[kk].w;
      bf16x8 bw[6];
#pragma unroll
      for (int ct = 0; ct < 6; ++ct) {
        int col = cg * 96 + ct * 16 + lo;
        bw[ct] = ldw<WS>(q_wb, qw_f, col * 192 + kk * 32 + hi * 8);
      }
#pragma unroll
      for (int ct = 0; ct < 6; ++ct) acc[ct] = mfma16(a, bw[ct], acc[ct]);
    }
#pragma unroll
    for (int ct = 0; ct < 6; ++ct) {
      int col = cg * 96 + ct * 16 + lo;
      float bv = qb[col];
#pragma unroll
      for (int i = 0; i < 4; ++i)
        *(bf16_t*)(R0 + swz(rt * 16 + hi * 4 + i, col * 2, 384)) =
            (bf16_t)((acc[ct][i] + bv) * SCALE);
    }
  }
  __syncthreads();  // Q ready

  // ---------- attention: wave = (rowtile w>>1, head-half w&1), swapped QK^T ----------
  // att-out overwrites R1 (K) per head: head hq's K cols are dead after its QK^T;
  // a barrier after PV orders all QK reads before the att-out writes.
  {
    const int rt3 = w >> 1, hh = w & 1, rbase = rt3 * 16;
    const int r = rbase + lo;  // this lane's softmax row (q)
    const float* maskp = mask + (size_t)(b & 1023) * 4096 + r * 64;
    f32x4 mk[4];
    int relidx[4][4];
#pragma unroll
    for (int ct = 0; ct < 4; ++ct) {
      mk[ct] = *(const f32x4*)(maskp + ct * 16 + hi * 4);
      if (!WS) {
#pragma unroll
        for (int i = 0; i < 4; ++i) {
          int c = ct * 16 + hi * 4 + i;
          relidx[ct][i] = (((r >> 3) - (c >> 3) + 7) * 15 + ((r & 7) - (c & 7) + 7)) * 6;
        }
      }
    }
#pragma unroll
    for (int hq = 0; hq < 3; ++hq) {
      const int h = hh * 3 + hq;
      bf16x8 qa = *(const bf16x8*)(R0 + swz(r, h * 64 + hi * 16, 384));
      f32x4 s[4];
#pragma unroll
      for (int ct = 0; ct < 4; ++ct) {
        f32x4 ci;
        if (WS) {
          ci = *(const f32x4*)(biasws + h * 4096 + r * 64 + ct * 16 + hi * 4);
        } else {
#pragma unroll
          for (int i = 0; i < 4; ++i) ci[i] = table[relidx[ct][i] + h];
        }
        ci += mk[ct];
        bf16x8 ka = *(const bf16x8*)(R1 + swz(ct * 16 + lo, h * 64 + hi * 16, 384));
        s[ct] = mfma16(ka, qa, ci);  // S^T: lane holds S[r][c=ct*16+hi*4+i]
      }
      float mx = -1e30f;
#pragma unroll
      for (int ct = 0; ct < 4; ++ct)
#pragma unroll
        for (int i = 0; i < 4; ++i) mx = fmaxf(mx, s[ct][i]);
      mx = fmaxf(mx, __shfl_xor(mx, 16));
      mx = fmaxf(mx, __shfl_xor(mx, 32));
      float sum = 0.f;
#pragma unroll
      for (int ct = 0; ct < 4; ++ct)
#pragma unroll
        for (int i = 0; i < 4; ++i) {
          float p = __expf(s[ct][i] - mx);
          s[ct][i] = p;
          sum += p;
        }
      sum += __shfl_xor(sum, 16);
      sum += __shfl_xor(sum, 32);
      float rinv = 1.0f / sum;
      unsigned int word[4][2];
#pragma unroll
      for (int ct = 0; ct < 4; ++ct)
#pragma unroll
        for (int i2 = 0; i2 < 2; ++i2) {
          CvtU cu;
          cu.h[0] = (bf16_t)(s[ct][2 * i2] * rinv);
          cu.h[1] = (bf16_t)(s[ct][2 * i2 + 1] * rinv);
          word[ct][i2] = cu.u;
        }
      // PV: build A-frag P[r'=rbase+lo][k-run] via shfl word-pulls
      f32x4 o0 = {0.f, 0.f, 0.f, 0.f}, o1 = {0.f, 0.f, 0.f, 0.f};
#pragma unroll
      for (int k2 = 0; k2 < 2; ++k2) {
        PaU pa;
#pragma unroll
        for (int j2 = 0; j2 < 4; ++j2) {
          int src = lo + ((hi & 1) << 5) + ((j2 >> 1) << 4);
          unsigned int wa = (unsigned int)__shfl((int)word[2 * k2][j2 & 1], src);
          unsigned int wb = (unsigned int)__shfl((int)word[2 * k2 + 1][j2 & 1], src);
          pa.u[j2] = (hi & 2) ? wb : wa;
        }
        bf16x8 v0 = *(const bf16x8*)(R2 + swz(h * 32 + lo, k2 * 64 + hi * 16, 128));
        bf16x8 v1 = *(const bf16x8*)(R2 + swz(h * 32 + 16 + lo, k2 * 64 + hi * 16, 128));
        o0 = mfma16(pa.v, v0, o0);
        o1 = mfma16(pa.v, v1, o1);
      }
      __syncthreads();  // all QK reads of head hq's K cols complete
#pragma unroll
      for (int i = 0; i < 4; ++i) {
        int rr = rbase + hi * 4 + i;
        *(bf16_t*)(R1 + swz(rr, h * 64 + lo * 2, 384)) = (bf16_t)o0[i];
        *(bf16_t*)(R1 + swz(rr, h * 64 + 32 + lo * 2, 384)) = (bf16_t)o1[i];
      }
    }
  }
  __syncthreads();  // att-out fully in R1

  // ---------- out proj: wave = (rowtile w&3, col-group w>>2) ----------
  {
    const int rt4 = w & 3, cg = w >> 2;
    f32x4 acc[6];
#pragma unroll
    for (int ct = 0; ct < 6; ++ct) { f32x4 z = {0.f, 0.f, 0.f, 0.f}; acc[ct] = z; }
#pragma unroll
    for (int kk = 0; kk < 6; ++kk) {
      bf16x8 a = *(const bf16x8*)(R1 + swz(rt4 * 16 + lo, (kk * 4 + hi) * 16, 384));
      bf16x8 bw[6];
#pragma unroll
      for (int ct = 0; ct < 6; ++ct) {
        int col = cg * 96 + ct * 16 + lo;
        bw[ct] = ldw<WS>(p_wb, pw_f, col * 192 + kk * 32 + hi * 8);
      }
#pragma unroll
      for (int ct = 0; ct < 6; ++ct) acc[ct] = mfma16(a, bw[ct], acc[ct]);
    }
    float* outp = out + (size_t)b * 12288;
#pragma unroll
    for (int ct = 0; ct < 6; ++ct) {
      int col = cg * 96 + ct * 16 + lo;
      float bv = pb[col];
#pragma unroll
      for (int i = 0; i < 4; ++i)
        outp[(rt4 * 16 + hi * 4 + i) * 192 + col] = acc[ct][i] + bv;
    }
  }
}

extern "C" void kernel_launch(void* const* d_in, const int* in_sizes, int n_in,
                              void* d_out, int out_size, void* d_ws, size_t ws_size,
                              hipStream_t stream) {
  const float* x1 = (const float*)d_in[0];
  const float* x2 = (const float*)d_in[1];
  const float* mask = (const float*)d_in[2];
  const float* qw = (const float*)d_in[3];
  const float* qb = (const float*)d_in[4];
  const float* kvw = (const float*)d_in[5];
  const float* kvb = (const float*)d_in[6];
  const float* pw = (const float*)d_in[7];
  const float* pb = (const float*)d_in[8];
  const float* table = (const float*)d_in[9];
  float* out = (float*)d_out;
  bf16_t* wsb = (bf16_t*)d_ws;
  float* biasws = (float*)((char*)d_ws + 294912);
  const int LDS_BYTES = 73728;
  if (ws_size >= 393216) {
    prep<<<240, 256, 0, stream>>>(qw, kvw, pw, table, wsb, biasws);
    wca_main<true><<<8192, 512, LDS_BYTES, stream>>>(x1, x2, mask, qw, qb, kvw, kvb,
                                                     pw, pb, table, wsb, biasws, out);
  } else {
    wca_main<false><<<8192, 512, LDS_BYTES, stream>>>(x1, x2, mask, qw, qb, kvw, kvb,
                                                      pw, pb, table, wsb, biasws, out);
  }
}